// Round 3
// baseline (261.632 us; speedup 1.0000x reference)
//
#include <hip/hip_runtime.h>
#include <hip/hip_bf16.h>

#define BB 256
#define NIN 1024
#define NL 128
#define NSTEPS 256
#define MS 16384  // one 128x128 matrix slot (elements)

typedef __attribute__((ext_vector_type(8))) short bf16x8_t;
typedef __attribute__((ext_vector_type(4))) float f32x4_t;

__device__ inline unsigned short f2bf(float f) {
    __hip_bfloat16 h = __float2bfloat16(f);
    return *reinterpret_cast<unsigned short*>(&h);
}

// ---------------- K0: setup --------------------------------------------------
// blocks 0..63: lat0 = x @ F (4 b-rows per block, f32 + bf16)
// blocks 64..127: copy/convert tr -> W/Wb slot 0; convert F -> Fb
__global__ __launch_bounds__(128) void k_setup(const float* __restrict__ x,
                                               const float* __restrict__ tf,
                                               const float* __restrict__ tr,
                                               float* __restrict__ W,
                                               unsigned short* __restrict__ Wb,
                                               unsigned short* __restrict__ Fb,
                                               float* __restrict__ lat0,
                                               unsigned short* __restrict__ lat0b) {
    int t = threadIdx.x;
    if (blockIdx.x < 64) {
        __shared__ float xr[4][NIN];
        int b0 = blockIdx.x * 4;
#pragma unroll
        for (int rr = 0; rr < 4; ++rr) {
            const float4* xs = (const float4*)(x + (size_t)(b0 + rr) * NIN);
            for (int i = t; i < NIN / 4; i += 128) ((float4*)xr[rr])[i] = xs[i];
        }
        __syncthreads();
        float a0 = 0.f, a1 = 0.f, a2 = 0.f, a3 = 0.f;
#pragma unroll 8
        for (int i = 0; i < NIN; ++i) {
            float v = tf[i * NL + t];
            a0 += xr[0][i] * v; a1 += xr[1][i] * v;
            a2 += xr[2][i] * v; a3 += xr[3][i] * v;
        }
        lat0[(size_t)(b0 + 0) * NL + t] = a0;
        lat0[(size_t)(b0 + 1) * NL + t] = a1;
        lat0[(size_t)(b0 + 2) * NL + t] = a2;
        lat0[(size_t)(b0 + 3) * NL + t] = a3;
        lat0b[(size_t)(b0 + 0) * NL + t] = f2bf(a0);
        lat0b[(size_t)(b0 + 1) * NL + t] = f2bf(a1);
        lat0b[(size_t)(b0 + 2) * NL + t] = f2bf(a2);
        lat0b[(size_t)(b0 + 3) * NL + t] = f2bf(a3);
    } else {
        int id = (blockIdx.x - 64) * 128 + t;  // 0..8191
        for (int i = id; i < MS; i += 8192) {
            float v = tr[i];
            W[i] = v;
            Wb[i] = f2bf(v);
        }
        for (int i = id; i < NIN * NL; i += 8192) Fb[i] = f2bf(tf[i]);
    }
}

// ---------------- K1: power-chain level: D_i = A_i @ B (f32) ----------------
// grid = nmat*4; block computes 32 rows of D_i; also emits bf16 copy.
__global__ __launch_bounds__(256) void k_pmm(const float* __restrict__ A0,
                                             const float* __restrict__ Bm,
                                             float* __restrict__ D0,
                                             unsigned short* __restrict__ Db0) {
    int i = blockIdx.x >> 2, rt = blockIdx.x & 3;
    const float* A = A0 + (size_t)i * MS;
    float* D = D0 + (size_t)i * MS;
    unsigned short* Db = Db0 + (size_t)i * MS;
    int r0 = rt * 32;
    __shared__ float Bl[NL * NL];     // 64 KB
    __shared__ float At[NL][36];      // transposed A tile, 18 KB
    int t = threadIdx.x;
    for (int idx = t; idx < MS / 4; idx += 256)
        ((float4*)Bl)[idx] = ((const float4*)Bm)[idx];
    for (int idx = t; idx < 32 * NL; idx += 256) {
        int m = idx >> 7, kk = idx & 127;
        At[kk][m] = A[(size_t)(r0 + m) * NL + kk];
    }
    __syncthreads();
    int j = t & 127, rg = t >> 7;
    float acc[16];
#pragma unroll
    for (int q = 0; q < 16; ++q) acc[q] = 0.f;
#pragma unroll 2
    for (int kk = 0; kk < NL; ++kk) {
        float bv = Bl[kk * NL + j];
        const f32x4_t* ap = (const f32x4_t*)&At[kk][rg * 16];
        f32x4_t a0 = ap[0], a1 = ap[1], a2 = ap[2], a3 = ap[3];
        acc[0] += a0[0] * bv;  acc[1] += a0[1] * bv;
        acc[2] += a0[2] * bv;  acc[3] += a0[3] * bv;
        acc[4] += a1[0] * bv;  acc[5] += a1[1] * bv;
        acc[6] += a1[2] * bv;  acc[7] += a1[3] * bv;
        acc[8] += a2[0] * bv;  acc[9] += a2[1] * bv;
        acc[10] += a2[2] * bv; acc[11] += a2[3] * bv;
        acc[12] += a3[0] * bv; acc[13] += a3[1] * bv;
        acc[14] += a3[2] * bv; acc[15] += a3[3] * bv;
    }
#pragma unroll
    for (int q = 0; q < 16; ++q) {
        size_t off = (size_t)(r0 + rg * 16 + q) * NL + j;
        D[off] = acc[q];
        Db[off] = f2bf(acc[q]);
    }
}

// ---------------- K2: G[(n*256+s)][m] = bf16(sum_l F[n,l] * T^{s+1}[m,l]) --
// grid = s(256, high) x nt(8, low); 128x128x128 NT MFMA
__global__ __launch_bounds__(256) void k_G(const unsigned short* __restrict__ Fb,
                                           const unsigned short* __restrict__ Wb,
                                           unsigned short* __restrict__ G) {
    int s = blockIdx.x >> 3;
    int nt = blockIdx.x & 7;
    __shared__ __align__(16) char lA[128 * 256];
    __shared__ __align__(16) char lB[128 * 256];
    int t = threadIdx.x;
    const unsigned short* Ag = Fb + (size_t)(nt * 128) * NL;
    const unsigned short* Bg = Wb + (size_t)s * MS;
    for (int i = t; i < 2048; i += 256) {
        int row = i >> 4, c = i & 15;
        int sw = (c * 16) ^ ((row & 7) << 4);
        *(bf16x8_t*)(lA + row * 256 + sw) =
            *(const bf16x8_t*)(Ag + (size_t)row * NL + c * 8);
        *(bf16x8_t*)(lB + row * 256 + sw) =
            *(const bf16x8_t*)(Bg + (size_t)row * NL + c * 8);
    }
    __syncthreads();
    int w = t >> 6, lane = t & 63;
    int wn = (w >> 1) * 64;   // wave n-offset
    int wm = (w & 1) * 64;    // wave m-offset
    int r = lane & 15, g = lane >> 4;
    f32x4_t acc[4][4];
#pragma unroll
    for (int mf = 0; mf < 4; ++mf)
#pragma unroll
        for (int nf = 0; nf < 4; ++nf) acc[mf][nf] = (f32x4_t){0.f, 0.f, 0.f, 0.f};
#pragma unroll
    for (int kk = 0; kk < 4; ++kk) {
        int c16 = kk * 4 + g;
        bf16x8_t av[4], bv[4];
#pragma unroll
        for (int mf = 0; mf < 4; ++mf) {
            int rowA = wn + mf * 16 + r;
            av[mf] = *(const bf16x8_t*)(lA + rowA * 256 + ((c16 * 16) ^ ((rowA & 7) << 4)));
            int rowB = wm + mf * 16 + r;
            bv[mf] = *(const bf16x8_t*)(lB + rowB * 256 + ((c16 * 16) ^ ((rowB & 7) << 4)));
        }
#pragma unroll
        for (int mf = 0; mf < 4; ++mf)
#pragma unroll
            for (int nf = 0; nf < 4; ++nf)
                acc[mf][nf] = __builtin_amdgcn_mfma_f32_16x16x32_bf16(av[mf], bv[nf], acc[mf][nf], 0, 0, 0);
    }
#pragma unroll
    for (int mf = 0; mf < 4; ++mf) {
#pragma unroll
        for (int nf = 0; nf < 4; ++nf) {
#pragma unroll
            for (int q = 0; q < 4; ++q) {
                int n_row = nt * 128 + wn + mf * 16 + g * 4 + q;
                int mcol = wm + nf * 16 + r;
                G[((size_t)n_row * NSTEPS + s) * NL + mcol] = f2bf(acc[mf][nf][q]);
            }
        }
    }
}

// ---------------- K3: out = lat0b @ G^T  [256 x 262144 x 128] --------------
// grid = bt(2, high) x ct(2048, low); B staged in LDS (32 KB), A direct.
__global__ __launch_bounds__(256) void k_main(const unsigned short* __restrict__ lat0b,
                                              const unsigned short* __restrict__ G,
                                              float* __restrict__ out) {
    int ct = blockIdx.x & 2047;
    int bt = blockIdx.x >> 11;
    __shared__ __align__(16) char lB[128 * 256];
    int t = threadIdx.x;
    const unsigned short* Bg = G + (size_t)(ct * 128) * NL;
    for (int i = t; i < 2048; i += 256) {
        int row = i >> 4, c = i & 15;
        int sw = (c * 16) ^ ((row & 7) << 4);
        *(bf16x8_t*)(lB + row * 256 + sw) =
            *(const bf16x8_t*)(Bg + (size_t)row * NL + c * 8);
    }
    __syncthreads();
    int w = t >> 6, lane = t & 63;
    int wbo = (w >> 1) * 64;  // wave b-offset
    int wc = (w & 1) * 64;    // wave col-offset
    int r = lane & 15, g = lane >> 4;
    const unsigned short* Arow = lat0b + (size_t)(bt * 128) * NL;
    f32x4_t acc[4][4];
#pragma unroll
    for (int mf = 0; mf < 4; ++mf)
#pragma unroll
        for (int nf = 0; nf < 4; ++nf) acc[mf][nf] = (f32x4_t){0.f, 0.f, 0.f, 0.f};
#pragma unroll
    for (int kk = 0; kk < 4; ++kk) {
        int c16 = kk * 4 + g;
        bf16x8_t av[4], bv[4];
#pragma unroll
        for (int mf = 0; mf < 4; ++mf) {
            int rowA = wbo + mf * 16 + r;
            av[mf] = *(const bf16x8_t*)(Arow + (size_t)rowA * NL + c16 * 8);
            int rowB = wc + mf * 16 + r;
            bv[mf] = *(const bf16x8_t*)(lB + rowB * 256 + ((c16 * 16) ^ ((rowB & 7) << 4)));
        }
#pragma unroll
        for (int mf = 0; mf < 4; ++mf)
#pragma unroll
            for (int nf = 0; nf < 4; ++nf)
                acc[mf][nf] = __builtin_amdgcn_mfma_f32_16x16x32_bf16(av[mf], bv[nf], acc[mf][nf], 0, 0, 0);
    }
#pragma unroll
    for (int mf = 0; mf < 4; ++mf) {
#pragma unroll
        for (int nf = 0; nf < 4; ++nf) {
#pragma unroll
            for (int q = 0; q < 4; ++q) {
                int brow = bt * 128 + wbo + mf * 16 + g * 4 + q;
                int col = ct * 128 + wc + nf * 16 + r;
                out[(size_t)brow * (NIN * NSTEPS) + col] = acc[mf][nf][q];
            }
        }
    }
}

extern "C" void kernel_launch(void* const* d_in, const int* in_sizes, int n_in,
                              void* d_out, int out_size, void* d_ws, size_t ws_size,
                              hipStream_t stream) {
    const float* x = (const float*)d_in[0];
    const float* tf = (const float*)d_in[1];
    const float* tr = (const float*)d_in[2];
    float* out = (float*)d_out;

    // workspace layout
    float* W = (float*)d_ws;                         // 256 slots f32: T^1..T^256
    float* lat0 = W + (size_t)256 * MS;              // [256][128] f32
    unsigned short* Wb = (unsigned short*)(lat0 + (size_t)BB * NL);  // 256 slots bf16
    unsigned short* Fb = Wb + (size_t)256 * MS;      // [1024][128] bf16
    unsigned short* lat0b = Fb + (size_t)NIN * NL;   // [256][128] bf16
    unsigned short* G = lat0b + (size_t)BB * NL;     // [262144][128] bf16 (67 MB)

    k_setup<<<128, 128, 0, stream>>>(x, tf, tr, W, Wb, Fb, lat0, lat0b);

    // chain: level m computes T^{m+1..2m} = T^{1..m} @ T^m (slots are power-1)
    for (int m = 1; m <= 128; m <<= 1) {
        k_pmm<<<m * 4, 256, 0, stream>>>(W, W + (size_t)(m - 1) * MS,
                                         W + (size_t)m * MS, Wb + (size_t)m * MS);
    }

    k_G<<<2048, 256, 0, stream>>>(Fb, Wb, G);
    k_main<<<4096, 256, 0, stream>>>(lat0b, G, out);
}

// Round 4
// 256.806 us; speedup vs baseline: 1.0188x; 1.0188x over previous
//
#include <hip/hip_runtime.h>
#include <hip/hip_bf16.h>

#define BB 256
#define NIN 1024
#define NL 128
#define NSTEPS 256
#define MS 16384  // one 128x128 matrix slot (elements)

typedef __attribute__((ext_vector_type(8))) short bf16x8_t;
typedef __attribute__((ext_vector_type(4))) float f32x4_t;

__device__ inline unsigned short f2bf(float f) {
    __hip_bfloat16 h = __float2bfloat16(f);
    return *reinterpret_cast<unsigned short*>(&h);
}

// ---------------- K0: setup --------------------------------------------------
__global__ __launch_bounds__(128) void k_setup(const float* __restrict__ x,
                                               const float* __restrict__ tf,
                                               const float* __restrict__ tr,
                                               float* __restrict__ W,
                                               unsigned short* __restrict__ Wb,
                                               unsigned short* __restrict__ Fb,
                                               float* __restrict__ lat0,
                                               unsigned short* __restrict__ lat0b) {
    int t = threadIdx.x;
    if (blockIdx.x < 64) {
        __shared__ float xr[4][NIN];
        int b0 = blockIdx.x * 4;
#pragma unroll
        for (int rr = 0; rr < 4; ++rr) {
            const float4* xs = (const float4*)(x + (size_t)(b0 + rr) * NIN);
            for (int i = t; i < NIN / 4; i += 128) ((float4*)xr[rr])[i] = xs[i];
        }
        __syncthreads();
        float a0 = 0.f, a1 = 0.f, a2 = 0.f, a3 = 0.f;
#pragma unroll 8
        for (int i = 0; i < NIN; ++i) {
            float v = tf[i * NL + t];
            a0 += xr[0][i] * v; a1 += xr[1][i] * v;
            a2 += xr[2][i] * v; a3 += xr[3][i] * v;
        }
        lat0[(size_t)(b0 + 0) * NL + t] = a0;
        lat0[(size_t)(b0 + 1) * NL + t] = a1;
        lat0[(size_t)(b0 + 2) * NL + t] = a2;
        lat0[(size_t)(b0 + 3) * NL + t] = a3;
        lat0b[(size_t)(b0 + 0) * NL + t] = f2bf(a0);
        lat0b[(size_t)(b0 + 1) * NL + t] = f2bf(a1);
        lat0b[(size_t)(b0 + 2) * NL + t] = f2bf(a2);
        lat0b[(size_t)(b0 + 3) * NL + t] = f2bf(a3);
    } else {
        int id = (blockIdx.x - 64) * 128 + t;  // 0..8191
        for (int i = id; i < MS; i += 8192) {
            float v = tr[i];
            W[i] = v;
            Wb[i] = f2bf(v);
        }
        for (int i = id; i < NIN * NL; i += 8192) Fb[i] = f2bf(tf[i]);
    }
}

// ---------------- K1: power-chain level: D_i = A_i @ B (f32) ----------------
__global__ __launch_bounds__(256) void k_pmm(const float* __restrict__ A0,
                                             const float* __restrict__ Bm,
                                             float* __restrict__ D0,
                                             unsigned short* __restrict__ Db0) {
    int i = blockIdx.x >> 2, rt = blockIdx.x & 3;
    const float* A = A0 + (size_t)i * MS;
    float* D = D0 + (size_t)i * MS;
    unsigned short* Db = Db0 + (size_t)i * MS;
    int r0 = rt * 32;
    __shared__ float Bl[NL * NL];     // 64 KB
    __shared__ float At[NL][36];
    int t = threadIdx.x;
    for (int idx = t; idx < MS / 4; idx += 256)
        ((float4*)Bl)[idx] = ((const float4*)Bm)[idx];
    for (int idx = t; idx < 32 * NL; idx += 256) {
        int m = idx >> 7, kk = idx & 127;
        At[kk][m] = A[(size_t)(r0 + m) * NL + kk];
    }
    __syncthreads();
    int j = t & 127, rg = t >> 7;
    float acc[16];
#pragma unroll
    for (int q = 0; q < 16; ++q) acc[q] = 0.f;
#pragma unroll 2
    for (int kk = 0; kk < NL; ++kk) {
        float bv = Bl[kk * NL + j];
        const f32x4_t* ap = (const f32x4_t*)&At[kk][rg * 16];
        f32x4_t a0 = ap[0], a1 = ap[1], a2 = ap[2], a3 = ap[3];
        acc[0] += a0[0] * bv;  acc[1] += a0[1] * bv;
        acc[2] += a0[2] * bv;  acc[3] += a0[3] * bv;
        acc[4] += a1[0] * bv;  acc[5] += a1[1] * bv;
        acc[6] += a1[2] * bv;  acc[7] += a1[3] * bv;
        acc[8] += a2[0] * bv;  acc[9] += a2[1] * bv;
        acc[10] += a2[2] * bv; acc[11] += a2[3] * bv;
        acc[12] += a3[0] * bv; acc[13] += a3[1] * bv;
        acc[14] += a3[2] * bv; acc[15] += a3[3] * bv;
    }
#pragma unroll
    for (int q = 0; q < 16; ++q) {
        size_t off = (size_t)(r0 + rg * 16 + q) * NL + j;
        D[off] = acc[q];
        Db[off] = f2bf(acc[q]);
    }
}

// ---------------- K2: G[(n*256+s)][m] = bf16(sum_l F[n,l] * T^{s+1}[m,l]) --
__global__ __launch_bounds__(256) void k_G(const unsigned short* __restrict__ Fb,
                                           const unsigned short* __restrict__ Wb,
                                           unsigned short* __restrict__ G) {
    int s = blockIdx.x >> 3;
    int nt = blockIdx.x & 7;
    __shared__ __align__(16) char lA[128 * 256];
    __shared__ __align__(16) char lB[128 * 256];
    int t = threadIdx.x;
    const unsigned short* Ag = Fb + (size_t)(nt * 128) * NL;
    const unsigned short* Bg = Wb + (size_t)s * MS;
    for (int i = t; i < 2048; i += 256) {
        int row = i >> 4, c = i & 15;
        int sw = (c * 16) ^ ((row & 7) << 4);
        *(bf16x8_t*)(lA + row * 256 + sw) =
            *(const bf16x8_t*)(Ag + (size_t)row * NL + c * 8);
        *(bf16x8_t*)(lB + row * 256 + sw) =
            *(const bf16x8_t*)(Bg + (size_t)row * NL + c * 8);
    }
    __syncthreads();
    int w = t >> 6, lane = t & 63;
    int wn = (w >> 1) * 64;
    int wm = (w & 1) * 64;
    int r = lane & 15, g = lane >> 4;
    f32x4_t acc[4][4];
#pragma unroll
    for (int mf = 0; mf < 4; ++mf)
#pragma unroll
        for (int nf = 0; nf < 4; ++nf) acc[mf][nf] = (f32x4_t){0.f, 0.f, 0.f, 0.f};
#pragma unroll
    for (int kk = 0; kk < 4; ++kk) {
        int c16 = kk * 4 + g;
        bf16x8_t av[4], bv[4];
#pragma unroll
        for (int mf = 0; mf < 4; ++mf) {
            int rowA = wn + mf * 16 + r;
            av[mf] = *(const bf16x8_t*)(lA + rowA * 256 + ((c16 * 16) ^ ((rowA & 7) << 4)));
            int rowB = wm + mf * 16 + r;
            bv[mf] = *(const bf16x8_t*)(lB + rowB * 256 + ((c16 * 16) ^ ((rowB & 7) << 4)));
        }
#pragma unroll
        for (int mf = 0; mf < 4; ++mf)
#pragma unroll
            for (int nf = 0; nf < 4; ++nf)
                acc[mf][nf] = __builtin_amdgcn_mfma_f32_16x16x32_bf16(av[mf], bv[nf], acc[mf][nf], 0, 0, 0);
    }
#pragma unroll
    for (int mf = 0; mf < 4; ++mf) {
#pragma unroll
        for (int nf = 0; nf < 4; ++nf) {
#pragma unroll
            for (int q = 0; q < 4; ++q) {
                int n_row = nt * 128 + wn + mf * 16 + g * 4 + q;
                int mcol = wm + nf * 16 + r;
                G[((size_t)n_row * NSTEPS + s) * NL + mcol] = f2bf(acc[mf][nf][q]);
            }
        }
    }
}

// ---------------- K3: out = lat0b @ G^T with LDS-transpose epilogue --------
// grid = ct(2048); bt looped inside; stores are dwordx4, 512B row segments.
__global__ __launch_bounds__(256) void k_main(const unsigned short* __restrict__ lat0b,
                                              const unsigned short* __restrict__ G,
                                              float* __restrict__ out) {
    int ct = blockIdx.x;
    __shared__ __align__(16) char lB[128 * 256];   // swizzled G tile (32 KB)
    __shared__ __align__(16) float lE[64 * 128];   // epilogue tile (32 KB)
    int t = threadIdx.x;
    const unsigned short* Bg = G + (size_t)ct * 128 * NL;
    for (int i = t; i < 2048; i += 256) {
        int row = i >> 4, c = i & 15;
        int sw = (c * 16) ^ ((row & 7) << 4);
        *(bf16x8_t*)(lB + row * 256 + sw) =
            *(const bf16x8_t*)(Bg + (size_t)row * NL + c * 8);
    }
    __syncthreads();
    int w = t >> 6, lane = t & 63;
    int wr = (w >> 1) * 64;   // wave b-row offset
    int wc = (w & 1) * 64;    // wave col offset
    int r = lane & 15, g = lane >> 4;

    for (int bt = 0; bt < 2; ++bt) {
        const unsigned short* Arow = lat0b + (size_t)(bt * 128) * NL;
        // preload all A fragments
        bf16x8_t av[4][4];  // [kk][mf]
#pragma unroll
        for (int kk = 0; kk < 4; ++kk) {
            int c16 = kk * 4 + g;
#pragma unroll
            for (int mf = 0; mf < 4; ++mf)
                av[kk][mf] = *(const bf16x8_t*)(Arow + (size_t)(wr + mf * 16 + r) * NL + c16 * 8);
        }
        f32x4_t acc[4][4];
#pragma unroll
        for (int mf = 0; mf < 4; ++mf)
#pragma unroll
            for (int nf = 0; nf < 4; ++nf) acc[mf][nf] = (f32x4_t){0.f, 0.f, 0.f, 0.f};
#pragma unroll
        for (int kk = 0; kk < 4; ++kk) {
            int c16 = kk * 4 + g;
            bf16x8_t bv[4];
#pragma unroll
            for (int nf = 0; nf < 4; ++nf) {
                int rowB = wc + nf * 16 + r;
                bv[nf] = *(const bf16x8_t*)(lB + rowB * 256 + ((c16 * 16) ^ ((rowB & 7) << 4)));
            }
#pragma unroll
            for (int mf = 0; mf < 4; ++mf)
#pragma unroll
                for (int nf = 0; nf < 4; ++nf)
                    acc[mf][nf] = __builtin_amdgcn_mfma_f32_16x16x32_bf16(av[kk][mf], bv[nf], acc[mf][nf], 0, 0, 0);
        }
        // epilogue: 2 passes x 64 rows, LDS transpose -> coalesced dwordx4
#pragma unroll
        for (int p = 0; p < 2; ++p) {
            __syncthreads();
            if ((w >> 1) == p) {
#pragma unroll
                for (int mf = 0; mf < 4; ++mf)
#pragma unroll
                    for (int nf = 0; nf < 4; ++nf)
#pragma unroll
                        for (int q = 0; q < 4; ++q)
                            lE[(mf * 16 + g * 4 + q) * 128 + wc + nf * 16 + r] = acc[mf][nf][q];
            }
            __syncthreads();
#pragma unroll
            for (int i2 = 0; i2 < 8; ++i2) {
                int id = i2 * 256 + t;
                int row_l = id >> 5, cc = id & 31;
                f32x4_t v = *(const f32x4_t*)&lE[row_l * 128 + cc * 4];
                *(f32x4_t*)&out[(size_t)(bt * 128 + p * 64 + row_l) * (NIN * NSTEPS) +
                                (size_t)ct * 128 + cc * 4] = v;
            }
        }
    }
}

extern "C" void kernel_launch(void* const* d_in, const int* in_sizes, int n_in,
                              void* d_out, int out_size, void* d_ws, size_t ws_size,
                              hipStream_t stream) {
    const float* x = (const float*)d_in[0];
    const float* tf = (const float*)d_in[1];
    const float* tr = (const float*)d_in[2];
    float* out = (float*)d_out;

    float* W = (float*)d_ws;                         // 256 slots f32: T^1..T^256
    float* lat0 = W + (size_t)256 * MS;
    unsigned short* Wb = (unsigned short*)(lat0 + (size_t)BB * NL);
    unsigned short* Fb = Wb + (size_t)256 * MS;
    unsigned short* lat0b = Fb + (size_t)NIN * NL;
    unsigned short* G = lat0b + (size_t)BB * NL;     // [262144][128] bf16 (67 MB)

    k_setup<<<128, 128, 0, stream>>>(x, tf, tr, W, Wb, Fb, lat0, lat0b);

    for (int m = 1; m <= 128; m <<= 1) {
        k_pmm<<<m * 4, 256, 0, stream>>>(W, W + (size_t)(m - 1) * MS,
                                         W + (size_t)m * MS, Wb + (size_t)m * MS);
    }

    k_G<<<2048, 256, 0, stream>>>(Fb, Wb, G);
    k_main<<<2048, 256, 0, stream>>>(lat0b, G, out);
}